// Round 1
// baseline (709.226 us; speedup 1.0000x reference)
//
#include <hip/hip_runtime.h>

typedef __attribute__((ext_vector_type(8))) short short8;
typedef __attribute__((ext_vector_type(4))) float floatx4;

#define C_DIM 50000
#define D_DIM 1024
#define N_DIM 256
#define G_NUM 4
#define NNZ_G 300000
#define E_TOT (G_NUM * NNZ_G)

// workspace layout (bytes)
#define O_SB   0u                      // scale[1024] + bias[1024] fp32 = 8192
#define O_H0   8192u                   // h0 bf16 [256][1024] = 524288
#define O_ZT   532480u                 // Zt bf16 [50000][256] = 25600000
#define O_CNT  26132480u               // counts int[50000] (pad to 200064)
#define O_OFF  26332544u               // offsets int[50001]
#define O_CUR  26532608u               // cursor  int[50000]
#define O_BS   26732672u               // block sums int[256]
#define O_EDG  26733696u               // edges int2[1200000] = 9600000
// total ~36.4 MB

static __device__ __forceinline__ unsigned short f2bf(float f) {
    union { float f; unsigned u; } v; v.f = f;
    unsigned r = v.u + 0x7fffu + ((v.u >> 16) & 1u);   // RNE
    return (unsigned short)(r >> 16);
}
static __device__ __forceinline__ float bf2f(unsigned short u) {
    union { unsigned u; float f; } v; v.u = ((unsigned)u) << 16;
    return v.f;
}

// ---- 1. BatchNorm stats: scale[d] = rsqrt(var+eps), bias[d] = -mean*scale
__global__ __launch_bounds__(256) void k_bnstats(const float* __restrict__ x,
                                                 float* __restrict__ scale,
                                                 float* __restrict__ bias) {
    int d = blockIdx.x * 256 + threadIdx.x;
    float s = 0.f, ss = 0.f;
    for (int n = 0; n < N_DIM; ++n) {
        float v = x[n * D_DIM + d];
        s += v; ss += v * v;
    }
    float mean = s * (1.f / N_DIM);
    float var  = ss * (1.f / N_DIM) - mean * mean;
    float sc = rsqrtf(var + 1e-5f);
    scale[d] = sc;
    bias[d] = -mean * sc;
}

// ---- 2. h0 = normalize(x) in bf16
__global__ __launch_bounds__(256) void k_h0(const float* __restrict__ x,
                                            const float* __restrict__ scale,
                                            const float* __restrict__ bias,
                                            unsigned short* __restrict__ h0) {
    int id = blockIdx.x * 256 + threadIdx.x;
    int d = id & (D_DIM - 1);
    h0[id] = f2bf(x[id] * scale[d] + bias[d]);
}

// ---- 3. GEMM: Zt[c][b] = swish(sum_k W[c][k]*h0[b][k] + wb[c]), bf16 out
// 128x128 tile, BK=32, 4 waves (2x2), 16x16x32 bf16 MFMA, m93-style staging.
__global__ __launch_bounds__(256) void k_gemm(const float* __restrict__ W,
                                              const float* __restrict__ wb,
                                              const unsigned short* __restrict__ h0,
                                              unsigned short* __restrict__ Zt) {
    __shared__ unsigned short As[128 * 40];   // padded stride 40 elems (80 B)
    __shared__ unsigned short Bs[128 * 40];
    const int t = threadIdx.x;
    const int c0 = blockIdx.x * 128;
    const int b0 = blockIdx.y * 128;
    const int w = t >> 6, lane = t & 63;
    const int wr = w >> 1, wc = w & 1;
    const int m = lane & 15, g = lane >> 4;
    const int srow = t >> 1, sseg = t & 1;

    floatx4 acc[4][4];
#pragma unroll
    for (int i = 0; i < 4; ++i)
#pragma unroll
        for (int j = 0; j < 4; ++j) acc[i][j] = (floatx4)0.f;

    for (int kk = 0; kk < D_DIM; kk += 32) {
        // stage A tile (fp32 -> bf16)
        {
            int c = c0 + srow;
            float4 f0, f1, f2, f3;
            if (c < C_DIM) {
                const float4* src = (const float4*)&W[(size_t)c * D_DIM + kk + sseg * 16];
                f0 = src[0]; f1 = src[1]; f2 = src[2]; f3 = src[3];
            } else {
                f0 = f1 = f2 = f3 = make_float4(0.f, 0.f, 0.f, 0.f);
            }
            unsigned p0 = (unsigned)f2bf(f0.x) | ((unsigned)f2bf(f0.y) << 16);
            unsigned p1 = (unsigned)f2bf(f0.z) | ((unsigned)f2bf(f0.w) << 16);
            unsigned p2 = (unsigned)f2bf(f1.x) | ((unsigned)f2bf(f1.y) << 16);
            unsigned p3 = (unsigned)f2bf(f1.z) | ((unsigned)f2bf(f1.w) << 16);
            unsigned p4 = (unsigned)f2bf(f2.x) | ((unsigned)f2bf(f2.y) << 16);
            unsigned p5 = (unsigned)f2bf(f2.z) | ((unsigned)f2bf(f2.w) << 16);
            unsigned p6 = (unsigned)f2bf(f3.x) | ((unsigned)f2bf(f3.y) << 16);
            unsigned p7 = (unsigned)f2bf(f3.z) | ((unsigned)f2bf(f3.w) << 16);
            uint4* dst = (uint4*)&As[srow * 40 + sseg * 16];
            dst[0] = make_uint4(p0, p1, p2, p3);
            dst[1] = make_uint4(p4, p5, p6, p7);
        }
        // stage B tile (bf16 passthrough)
        {
            const uint4* src = (const uint4*)&h0[(size_t)(b0 + srow) * D_DIM + kk + sseg * 16];
            uint4* dst = (uint4*)&Bs[srow * 40 + sseg * 16];
            dst[0] = src[0];
            dst[1] = src[1];
        }
        __syncthreads();

        short8 af[4], bfr[4];
#pragma unroll
        for (int i = 0; i < 4; ++i)
            af[i] = *(const short8*)&As[(wr * 64 + i * 16 + m) * 40 + g * 8];
#pragma unroll
        for (int j = 0; j < 4; ++j)
            bfr[j] = *(const short8*)&Bs[(wc * 64 + j * 16 + m) * 40 + g * 8];
#pragma unroll
        for (int i = 0; i < 4; ++i)
#pragma unroll
            for (int j = 0; j < 4; ++j)
                acc[i][j] = __builtin_amdgcn_mfma_f32_16x16x32_bf16(af[i], bfr[j], acc[i][j], 0, 0, 0);
        __syncthreads();
    }

    // epilogue: bias + swish, store bf16 to Zt[c][b]
    const int n = lane & 15;
#pragma unroll
    for (int i = 0; i < 4; ++i) {
#pragma unroll
        for (int j = 0; j < 4; ++j) {
            int b = b0 + wc * 64 + j * 16 + n;
#pragma unroll
            for (int rr = 0; rr < 4; ++rr) {
                int c = c0 + wr * 64 + i * 16 + g * 4 + rr;
                if (c < C_DIM) {
                    float x = acc[i][j][rr] + wb[c];
                    float z = x / (1.f + __expf(-x));
                    Zt[(size_t)c * 256 + b] = f2bf(z);
                }
            }
        }
    }
}

// ---- 4. CSR build
__global__ __launch_bounds__(256) void k_count(const int* __restrict__ rows,
                                               int* __restrict__ counts) {
    int id = blockIdx.x * 256 + threadIdx.x;
    if (id < E_TOT) atomicAdd(&counts[rows[id]], 1);
}

__global__ __launch_bounds__(256) void k_scan1(const int* __restrict__ counts,
                                               int* __restrict__ offsets,
                                               int* __restrict__ bsums) {
    __shared__ int sm[256];
    int t = threadIdx.x, i = blockIdx.x * 256 + t;
    int v = (i < C_DIM) ? counts[i] : 0;
    sm[t] = v; __syncthreads();
    for (int off = 1; off < 256; off <<= 1) {
        int x = (t >= off) ? sm[t - off] : 0;
        __syncthreads();
        sm[t] += x;
        __syncthreads();
    }
    if (i < C_DIM) offsets[i] = sm[t] - v;     // block-local exclusive
    if (t == 255) bsums[blockIdx.x] = sm[255]; // block total
}

__global__ __launch_bounds__(256) void k_scan2(int* __restrict__ bsums,
                                               int* __restrict__ offsets) {
    __shared__ int sm[256];
    int t = threadIdx.x;
    int v = (t < 196) ? bsums[t] : 0;
    sm[t] = v; __syncthreads();
    for (int off = 1; off < 256; off <<= 1) {
        int x = (t >= off) ? sm[t - off] : 0;
        __syncthreads();
        sm[t] += x;
        __syncthreads();
    }
    if (t < 196) bsums[t] = sm[t] - v;         // exclusive block offsets
    if (t == 0) offsets[C_DIM] = sm[255];      // grand total (=1.2M)
}

__global__ __launch_bounds__(256) void k_scan3(const int* __restrict__ bsums,
                                               int* __restrict__ offsets,
                                               int* __restrict__ cursor) {
    int i = blockIdx.x * 256 + threadIdx.x;
    if (i < C_DIM) {
        int off = offsets[i] + bsums[blockIdx.x];
        offsets[i] = off;
        cursor[i] = off;
    }
}

__global__ __launch_bounds__(256) void k_scatter(const int* __restrict__ rows,
                                                 const int* __restrict__ cols,
                                                 const float* __restrict__ vals,
                                                 const float* __restrict__ vec,
                                                 int* __restrict__ cursor,
                                                 int2* __restrict__ edges) {
    int id = blockIdx.x * 256 + threadIdx.x;
    if (id < E_TOT) {
        int gidx = id / NNZ_G;
        float v = vals[id] * vec[gidx];
        int r = rows[id];
        int c = cols[id];
        int pos = atomicAdd(&cursor[r], 1);
        edges[pos] = make_int2(c, __float_as_int(v));
    }
}

// ---- 5. Aggregation + residual: one wave per row r; lane holds b = lane*4..+3
__global__ __launch_bounds__(256) void k_agg(const unsigned short* __restrict__ Zt,
                                             const int* __restrict__ offsets,
                                             const int2* __restrict__ edges,
                                             float* __restrict__ out) {
    int w = threadIdx.x >> 6;
    int lane = threadIdx.x & 63;
    int r = __builtin_amdgcn_readfirstlane(blockIdx.x * 4 + w);
    const int base = lane * 4;

    ushort4 z = *(const ushort4*)&Zt[(size_t)r * 256 + base];
    float a0 = bf2f(z.x), a1 = bf2f(z.y), a2 = bf2f(z.z), a3 = bf2f(z.w);

    int s = offsets[r], e = offsets[r + 1];
    for (; s + 4 <= e; s += 4) {
        int2 e0 = edges[s], e1 = edges[s + 1], e2 = edges[s + 2], e3 = edges[s + 3];
        ushort4 g0 = *(const ushort4*)&Zt[(size_t)e0.x * 256 + base];
        ushort4 g1 = *(const ushort4*)&Zt[(size_t)e1.x * 256 + base];
        ushort4 g2 = *(const ushort4*)&Zt[(size_t)e2.x * 256 + base];
        ushort4 g3 = *(const ushort4*)&Zt[(size_t)e3.x * 256 + base];
        float v0 = __int_as_float(e0.y), v1 = __int_as_float(e1.y);
        float v2 = __int_as_float(e2.y), v3 = __int_as_float(e3.y);
        a0 += v0 * bf2f(g0.x) + v1 * bf2f(g1.x) + v2 * bf2f(g2.x) + v3 * bf2f(g3.x);
        a1 += v0 * bf2f(g0.y) + v1 * bf2f(g1.y) + v2 * bf2f(g2.y) + v3 * bf2f(g3.y);
        a2 += v0 * bf2f(g0.z) + v1 * bf2f(g1.z) + v2 * bf2f(g2.z) + v3 * bf2f(g3.z);
        a3 += v0 * bf2f(g0.w) + v1 * bf2f(g1.w) + v2 * bf2f(g2.w) + v3 * bf2f(g3.w);
    }
    for (; s < e; ++s) {
        int2 e0 = edges[s];
        ushort4 g0 = *(const ushort4*)&Zt[(size_t)e0.x * 256 + base];
        float v0 = __int_as_float(e0.y);
        a0 += v0 * bf2f(g0.x);
        a1 += v0 * bf2f(g0.y);
        a2 += v0 * bf2f(g0.z);
        a3 += v0 * bf2f(g0.w);
    }
    size_t ob = (size_t)base * C_DIM + r;
    out[ob] = a0;
    out[ob + C_DIM] = a1;
    out[ob + 2 * (size_t)C_DIM] = a2;
    out[ob + 3 * (size_t)C_DIM] = a3;
}

extern "C" void kernel_launch(void* const* d_in, const int* in_sizes, int n_in,
                              void* d_out, int out_size, void* d_ws, size_t ws_size,
                              hipStream_t stream) {
    (void)in_sizes; (void)n_in; (void)out_size; (void)ws_size;
    const float* x     = (const float*)d_in[0];   // output [256,1024]
    const float* W     = (const float*)d_in[1];   // wt2_w [50000,1024]
    const float* wb    = (const float*)d_in[2];   // wt2_b [50000]
    const float* Avals = (const float*)d_in[3];   // [4,300000]
    const float* vec   = (const float*)d_in[4];   // [4]
    const int*   Arows = (const int*)d_in[5];     // [4,300000]
    const int*   Acols = (const int*)d_in[6];     // [4,300000]
    float* out = (float*)d_out;
    char* ws = (char*)d_ws;

    float* scale = (float*)(ws + O_SB);
    float* bias  = scale + 1024;
    unsigned short* h0 = (unsigned short*)(ws + O_H0);
    unsigned short* Zt = (unsigned short*)(ws + O_ZT);
    int* counts  = (int*)(ws + O_CNT);
    int* offsets = (int*)(ws + O_OFF);
    int* cursor  = (int*)(ws + O_CUR);
    int* bsums   = (int*)(ws + O_BS);
    int2* edges  = (int2*)(ws + O_EDG);

    hipMemsetAsync(counts, 0, C_DIM * sizeof(int), stream);

    k_bnstats<<<4, 256, 0, stream>>>(x, scale, bias);
    k_h0<<<1024, 256, 0, stream>>>(x, scale, bias, h0);
    k_count<<<(E_TOT + 255) / 256, 256, 0, stream>>>(Arows, counts);
    k_gemm<<<dim3((C_DIM + 127) / 128, 2), 256, 0, stream>>>(W, wb, h0, Zt);
    k_scan1<<<196, 256, 0, stream>>>(counts, offsets, bsums);
    k_scan2<<<1, 256, 0, stream>>>(bsums, offsets);
    k_scan3<<<196, 256, 0, stream>>>(bsums, offsets, cursor);
    k_scatter<<<(E_TOT + 255) / 256, 256, 0, stream>>>(Arows, Acols, Avals, vec, cursor, edges);
    k_agg<<<C_DIM / 4, 256, 0, stream>>>(Zt, offsets, edges, out);
}

// Round 2
// 662.234 us; speedup vs baseline: 1.0710x; 1.0710x over previous
//
#include <hip/hip_runtime.h>

typedef __attribute__((ext_vector_type(8))) short short8;
typedef __attribute__((ext_vector_type(4))) float floatx4;

#define C_DIM 50000
#define D_DIM 1024
#define N_DIM 256
#define G_NUM 4
#define NNZ_G 300000
#define E_TOT (G_NUM * NNZ_G)

// workspace layout (bytes)
#define O_SB   0u                      // scale[1024] + bias[1024] fp32 = 8192
#define O_H0   8192u                   // h0 bf16 [256][1024] = 524288
#define O_ZT   532480u                 // Zt bf16 [50000][256] = 25600000
#define O_CNT  26132480u               // counts int[50000]
#define O_OFF  26332544u               // offsets int[50001]
#define O_CUR  26532608u               // cursor  int[50000]
#define O_BS   26732672u               // block sums int[256]
#define O_EDG  26733696u               // edges int2[1200000] = 9600000

static __device__ __forceinline__ unsigned short f2bf(float f) {
    union { float f; unsigned u; } v; v.f = f;
    unsigned r = v.u + 0x7fffu + ((v.u >> 16) & 1u);   // RNE
    return (unsigned short)(r >> 16);
}
static __device__ __forceinline__ float bf2f(unsigned short u) {
    union { unsigned u; float f; } v; v.u = ((unsigned)u) << 16;
    return v.f;
}

// ---- 1. BatchNorm stats
__global__ __launch_bounds__(256) void k_bnstats(const float* __restrict__ x,
                                                 float* __restrict__ scale,
                                                 float* __restrict__ bias) {
    int d = blockIdx.x * 256 + threadIdx.x;
    float s = 0.f, ss = 0.f;
    for (int n = 0; n < N_DIM; ++n) {
        float v = x[n * D_DIM + d];
        s += v; ss += v * v;
    }
    float mean = s * (1.f / N_DIM);
    float var  = ss * (1.f / N_DIM) - mean * mean;
    float sc = rsqrtf(var + 1e-5f);
    scale[d] = sc;
    bias[d] = -mean * sc;
}

// ---- 2. h0 = normalize(x) in bf16
__global__ __launch_bounds__(256) void k_h0(const float* __restrict__ x,
                                            const float* __restrict__ scale,
                                            const float* __restrict__ bias,
                                            unsigned short* __restrict__ h0) {
    int id = blockIdx.x * 256 + threadIdx.x;
    int d = id & (D_DIM - 1);
    h0[id] = f2bf(x[id] * scale[d] + bias[d]);
}

// ---- 3. GEMM: Zt[c][b] = swish(W@h0 + wb), 64(C)x256(N) tile, W read ONCE.
// 4 waves; wave w owns N-chunk [w*64, w*64+64). 16x16x32 bf16 MFMA, 4x4 acc.
__global__ __launch_bounds__(256) void k_gemm(const float* __restrict__ W,
                                              const float* __restrict__ wb,
                                              const unsigned short* __restrict__ h0,
                                              unsigned short* __restrict__ Zt) {
    __shared__ unsigned short As[64 * 40];    // stride 40 elems (80 B) - conflict-spread
    __shared__ unsigned short Bs[256 * 40];
    const int t = threadIdx.x;
    const int c0 = blockIdx.x * 64;
    const int w = t >> 6, lane = t & 63;
    const int m = lane & 15, g = lane >> 4;
    const int arow = t >> 2, aseg = t & 3;

    floatx4 acc[4][4];
#pragma unroll
    for (int i = 0; i < 4; ++i)
#pragma unroll
        for (int j = 0; j < 4; ++j) acc[i][j] = (floatx4)0.f;

    for (int kk = 0; kk < D_DIM; kk += 32) {
        // stage A tile: 64 rows x 32 fp32 -> bf16. thread: row=t>>2, 8 floats.
        {
            int c = c0 + arow;
            float4 f0, f1;
            if (c < C_DIM) {
                const float4* src = (const float4*)&W[(size_t)c * D_DIM + kk + aseg * 8];
                f0 = src[0]; f1 = src[1];
            } else {
                f0 = f1 = make_float4(0.f, 0.f, 0.f, 0.f);
            }
            unsigned p0 = (unsigned)f2bf(f0.x) | ((unsigned)f2bf(f0.y) << 16);
            unsigned p1 = (unsigned)f2bf(f0.z) | ((unsigned)f2bf(f0.w) << 16);
            unsigned p2 = (unsigned)f2bf(f1.x) | ((unsigned)f2bf(f1.y) << 16);
            unsigned p3 = (unsigned)f2bf(f1.z) | ((unsigned)f2bf(f1.w) << 16);
            *(uint4*)&As[arow * 40 + aseg * 8] = make_uint4(p0, p1, p2, p3);
        }
        // stage B tile: 256 rows x 32 bf16, thread t stages its own row (64 B)
        {
            const uint4* src = (const uint4*)&h0[(size_t)t * D_DIM + kk];
            uint4* dst = (uint4*)&Bs[t * 40];
            dst[0] = src[0]; dst[1] = src[1]; dst[2] = src[2]; dst[3] = src[3];
        }
        __syncthreads();

        short8 af[4], bfr[4];
#pragma unroll
        for (int i = 0; i < 4; ++i)
            af[i] = *(const short8*)&As[(i * 16 + m) * 40 + g * 8];
#pragma unroll
        for (int j = 0; j < 4; ++j)
            bfr[j] = *(const short8*)&Bs[(w * 64 + j * 16 + m) * 40 + g * 8];
#pragma unroll
        for (int i = 0; i < 4; ++i)
#pragma unroll
            for (int j = 0; j < 4; ++j)
                acc[i][j] = __builtin_amdgcn_mfma_f32_16x16x32_bf16(af[i], bfr[j], acc[i][j], 0, 0, 0);
        __syncthreads();
    }

    // epilogue: bias + swish, store bf16 to Zt[c][b]
#pragma unroll
    for (int i = 0; i < 4; ++i) {
#pragma unroll
        for (int j = 0; j < 4; ++j) {
            int b = w * 64 + j * 16 + m;
#pragma unroll
            for (int rr = 0; rr < 4; ++rr) {
                int c = c0 + i * 16 + g * 4 + rr;
                if (c < C_DIM) {
                    float x = acc[i][j][rr] + wb[c];
                    float z = x / (1.f + __expf(-x));
                    Zt[(size_t)c * 256 + b] = f2bf(z);
                }
            }
        }
    }
}

// ---- 4. CSR build
__global__ __launch_bounds__(256) void k_count(const int* __restrict__ rows,
                                               int* __restrict__ counts) {
    int id = blockIdx.x * 256 + threadIdx.x;
    if (id < E_TOT) atomicAdd(&counts[rows[id]], 1);
}

__global__ __launch_bounds__(256) void k_scan1(const int* __restrict__ counts,
                                               int* __restrict__ offsets,
                                               int* __restrict__ bsums) {
    __shared__ int sm[256];
    int t = threadIdx.x, i = blockIdx.x * 256 + t;
    int v = (i < C_DIM) ? counts[i] : 0;
    sm[t] = v; __syncthreads();
    for (int off = 1; off < 256; off <<= 1) {
        int x = (t >= off) ? sm[t - off] : 0;
        __syncthreads();
        sm[t] += x;
        __syncthreads();
    }
    if (i < C_DIM) offsets[i] = sm[t] - v;
    if (t == 255) bsums[blockIdx.x] = sm[255];
}

__global__ __launch_bounds__(256) void k_scan2(int* __restrict__ bsums,
                                               int* __restrict__ offsets) {
    __shared__ int sm[256];
    int t = threadIdx.x;
    int v = (t < 196) ? bsums[t] : 0;
    sm[t] = v; __syncthreads();
    for (int off = 1; off < 256; off <<= 1) {
        int x = (t >= off) ? sm[t - off] : 0;
        __syncthreads();
        sm[t] += x;
        __syncthreads();
    }
    if (t < 196) bsums[t] = sm[t] - v;
    if (t == 0) offsets[C_DIM] = sm[255];
}

__global__ __launch_bounds__(256) void k_scan3(const int* __restrict__ bsums,
                                               int* __restrict__ offsets,
                                               int* __restrict__ cursor) {
    int i = blockIdx.x * 256 + threadIdx.x;
    if (i < C_DIM) {
        int off = offsets[i] + bsums[blockIdx.x];
        offsets[i] = off;
        cursor[i] = off;
    }
}

__global__ __launch_bounds__(256) void k_scatter(const int* __restrict__ rows,
                                                 const int* __restrict__ cols,
                                                 const float* __restrict__ vals,
                                                 const float* __restrict__ vec,
                                                 int* __restrict__ cursor,
                                                 int2* __restrict__ edges) {
    int id = blockIdx.x * 256 + threadIdx.x;
    if (id < E_TOT) {
        int gidx = id / NNZ_G;
        float v = vals[id] * vec[gidx];
        int r = rows[id];
        int c = cols[id];
        int pos = atomicAdd(&cursor[r], 1);
        edges[pos] = make_int2(c, __float_as_int(v));
    }
}

// ---- 5. Aggregation + residual. Block = 4 waves = 32 rows (wave: 8 rows seq).
// Register gather-sum per row -> LDS [32][256] -> coalesced 128 B/thread write.
__global__ __launch_bounds__(256) void k_agg(const unsigned short* __restrict__ Zt,
                                             const int* __restrict__ offsets,
                                             const int2* __restrict__ edges,
                                             float* __restrict__ out) {
    __shared__ float sm[32 * 256];
    const int t = threadIdx.x;
    const int w = t >> 6, lane = t & 63;
    const int r0 = blockIdx.x * 32;
    const int base = lane * 4;

#pragma unroll 1
    for (int k = 0; k < 8; ++k) {
        int lrow = w * 8 + k;
        int r = __builtin_amdgcn_readfirstlane(r0 + lrow);
        if (r < C_DIM) {
            ushort4 z = *(const ushort4*)&Zt[(size_t)r * 256 + base];
            float a0 = bf2f(z.x), a1 = bf2f(z.y), a2 = bf2f(z.z), a3 = bf2f(z.w);
            int s = offsets[r], e = offsets[r + 1];
            for (; s + 4 <= e; s += 4) {
                int2 e0 = edges[s], e1 = edges[s + 1], e2 = edges[s + 2], e3 = edges[s + 3];
                ushort4 g0 = *(const ushort4*)&Zt[(size_t)e0.x * 256 + base];
                ushort4 g1 = *(const ushort4*)&Zt[(size_t)e1.x * 256 + base];
                ushort4 g2 = *(const ushort4*)&Zt[(size_t)e2.x * 256 + base];
                ushort4 g3 = *(const ushort4*)&Zt[(size_t)e3.x * 256 + base];
                float v0 = __int_as_float(e0.y), v1 = __int_as_float(e1.y);
                float v2 = __int_as_float(e2.y), v3 = __int_as_float(e3.y);
                a0 += v0 * bf2f(g0.x) + v1 * bf2f(g1.x) + v2 * bf2f(g2.x) + v3 * bf2f(g3.x);
                a1 += v0 * bf2f(g0.y) + v1 * bf2f(g1.y) + v2 * bf2f(g2.y) + v3 * bf2f(g3.y);
                a2 += v0 * bf2f(g0.z) + v1 * bf2f(g1.z) + v2 * bf2f(g2.z) + v3 * bf2f(g3.z);
                a3 += v0 * bf2f(g0.w) + v1 * bf2f(g1.w) + v2 * bf2f(g2.w) + v3 * bf2f(g3.w);
            }
            for (; s < e; ++s) {
                int2 e0 = edges[s];
                ushort4 g0 = *(const ushort4*)&Zt[(size_t)e0.x * 256 + base];
                float v0 = __int_as_float(e0.y);
                a0 += v0 * bf2f(g0.x);
                a1 += v0 * bf2f(g0.y);
                a2 += v0 * bf2f(g0.z);
                a3 += v0 * bf2f(g0.w);
            }
            *(float4*)&sm[lrow * 256 + base] = make_float4(a0, a1, a2, a3);
        }
    }
    __syncthreads();

    // write phase: thread t = batch b, writes out[b][r0 .. r0+rows) contiguous
    int rows = C_DIM - r0; if (rows > 32) rows = 32;   // 32 or 16 (tail)
    int nq = rows >> 2;
    float4* op = (float4*)&out[(size_t)t * C_DIM + r0];
#pragma unroll 1
    for (int q = 0; q < nq; ++q) {
        float4 o;
        o.x = sm[(q * 4 + 0) * 256 + t];
        o.y = sm[(q * 4 + 1) * 256 + t];
        o.z = sm[(q * 4 + 2) * 256 + t];
        o.w = sm[(q * 4 + 3) * 256 + t];
        op[q] = o;
    }
}

extern "C" void kernel_launch(void* const* d_in, const int* in_sizes, int n_in,
                              void* d_out, int out_size, void* d_ws, size_t ws_size,
                              hipStream_t stream) {
    (void)in_sizes; (void)n_in; (void)out_size; (void)ws_size;
    const float* x     = (const float*)d_in[0];
    const float* W     = (const float*)d_in[1];
    const float* wb    = (const float*)d_in[2];
    const float* Avals = (const float*)d_in[3];
    const float* vec   = (const float*)d_in[4];
    const int*   Arows = (const int*)d_in[5];
    const int*   Acols = (const int*)d_in[6];
    float* out = (float*)d_out;
    char* ws = (char*)d_ws;

    float* scale = (float*)(ws + O_SB);
    float* bias  = scale + 1024;
    unsigned short* h0 = (unsigned short*)(ws + O_H0);
    unsigned short* Zt = (unsigned short*)(ws + O_ZT);
    int* counts  = (int*)(ws + O_CNT);
    int* offsets = (int*)(ws + O_OFF);
    int* cursor  = (int*)(ws + O_CUR);
    int* bsums   = (int*)(ws + O_BS);
    int2* edges  = (int2*)(ws + O_EDG);

    hipMemsetAsync(counts, 0, C_DIM * sizeof(int), stream);

    k_bnstats<<<4, 256, 0, stream>>>(x, scale, bias);
    k_h0<<<1024, 256, 0, stream>>>(x, scale, bias, h0);
    k_count<<<(E_TOT + 255) / 256, 256, 0, stream>>>(Arows, counts);
    k_gemm<<<(C_DIM + 63) / 64, 256, 0, stream>>>(W, wb, h0, Zt);
    k_scan1<<<196, 256, 0, stream>>>(counts, offsets, bsums);
    k_scan2<<<1, 256, 0, stream>>>(bsums, offsets);
    k_scan3<<<196, 256, 0, stream>>>(bsums, offsets, cursor);
    k_scatter<<<(E_TOT + 255) / 256, 256, 0, stream>>>(Arows, Acols, Avals, vec, cursor, edges);
    k_agg<<<(C_DIM + 31) / 32, 256, 0, stream>>>(Zt, offsets, edges, out);
}